// Round 1
// baseline (8114.414 us; speedup 1.0000x reference)
//
#include <hip/hip_runtime.h>
#include <hip/hip_bf16.h>
#include <stdint.h>

// Problem constants (DBlock: N=16, Cin=256, Cout=512, H=W=64)
static constexpr int N_   = 16;
static constexpr int CIN  = 256;
static constexpr int COUT = 512;
static constexpr int H_   = 64;
static constexpr int W_   = 64;
static constexpr int HW   = H_ * W_;   // 4096
static constexpr int HF   = 65;        // fir1 output spatial
static constexpr int HFF  = HF * HF;   // 4225
static constexpr int OH_  = 32;
static constexpr int OHW  = OH_ * OH_; // 1024

#define G3 (1.0f / 48.0f)   // 1/sqrt(256*9)
#define G1 (1.0f / 16.0f)   // 1/sqrt(256)
#define SQRT2F 1.4142135623730951f

__device__ __forceinline__ float actf(float v) {
    return (v > 0.0f ? v : 0.2f * v) * SQRT2F;
}
__device__ __forceinline__ float bf2f(__hip_bfloat16 b) { return __bfloat162float(b); }
__device__ __forceinline__ __hip_bfloat16 f2bf(float f) { return __float2bfloat16(f); }

// ---------------------------------------------------------------------------
// Kernel 1: x1 = act(conv3x3(lat, w_conv*g3, pad=1))   [16,256,64,64] bf16 out
// Block: 256 thr = 16 h-rows x 16 w-quads. Grid = N*256*(H/16) = 16384.
// Each thread: 4 outputs along w. Weights block-uniform -> scalar loads.
// ---------------------------------------------------------------------------
__global__ __launch_bounds__(256) void k_conv1(const float* __restrict__ lat,
                                               const float* __restrict__ wc,
                                               __hip_bfloat16* __restrict__ x1) {
    int b  = blockIdx.x;
    int h  = (b & 3) * 16 + (threadIdx.x >> 4);
    int w0 = (threadIdx.x & 15) * 4;
    int co = (b >> 2) & 255;
    int n  = b >> 10;

    const float* wbase = wc  + (size_t)co * (CIN * 9);
    const float* ibase = lat + (size_t)(n * CIN) * HW;

    float a0 = 0.f, a1 = 0.f, a2 = 0.f, a3 = 0.f;
    for (int ci = 0; ci < CIN; ++ci) {
        const float* wr  = wbase + ci * 9;
        const float* ich = ibase + ci * HW;
        #pragma unroll
        for (int kh = 0; kh < 3; ++kh) {
            int row = h + kh - 1;
            if (row < 0 || row >= H_) continue;
            const float* irow = ich + row * W_;
            float4 cv = *(const float4*)(irow + w0);
            float  lv = (w0 > 0)      ? irow[w0 - 1] : 0.f;
            float  rv = (w0 < W_ - 4) ? irow[w0 + 4] : 0.f;
            float ww0 = wr[kh * 3 + 0], ww1 = wr[kh * 3 + 1], ww2 = wr[kh * 3 + 2];
            a0 += ww0 * lv    + ww1 * cv.x + ww2 * cv.y;
            a1 += ww0 * cv.x  + ww1 * cv.y + ww2 * cv.z;
            a2 += ww0 * cv.y  + ww1 * cv.z + ww2 * cv.w;
            a3 += ww0 * cv.z  + ww1 * cv.w + ww2 * rv;
        }
    }
    alignas(8) __hip_bfloat16 o[4];
    o[0] = f2bf(actf(a0 * G3));
    o[1] = f2bf(actf(a1 * G3));
    o[2] = f2bf(actf(a2 * G3));
    o[3] = f2bf(actf(a3 * G3));
    size_t oi = ((size_t)(n * CIN + co) * H_ + h) * W_ + w0;
    *(uint2*)(x1 + oi) = *(const uint2*)o;
}

// ---------------------------------------------------------------------------
// Kernel 2: xf = FIR4x4(x1, pad=2, down=1)  -> [16,256,65,65] bf16
// ---------------------------------------------------------------------------
__global__ __launch_bounds__(256) void k_fir1(const __hip_bfloat16* __restrict__ x1,
                                              __hip_bfloat16* __restrict__ xf) {
    int idx = blockIdx.x * 256 + threadIdx.x;
    if (idx >= N_ * CIN * HFF) return;
    int ow = idx % HF;
    int t  = idx / HF;
    int oh = t % HF;
    int u  = t / HF;  // n*CIN + c
    const __hip_bfloat16* src = x1 + (size_t)u * HW;
    const float fk[4] = {0.125f, 0.375f, 0.375f, 0.125f};
    float acc = 0.f;
    #pragma unroll
    for (int i = 0; i < 4; ++i) {
        int r = oh + i - 2;
        if (r < 0 || r >= H_) continue;
        #pragma unroll
        for (int j = 0; j < 4; ++j) {
            int c = ow + j - 2;
            if (c < 0 || c >= W_) continue;
            acc += fk[i] * fk[j] * bf2f(src[r * W_ + c]);
        }
    }
    xf[idx] = f2bf(acc);
}

// ---------------------------------------------------------------------------
// Kernel 3: s2 = FIR4x4(lat, pad=1, down=2) -> [16,256,32,32] bf16
// ---------------------------------------------------------------------------
__global__ __launch_bounds__(256) void k_fir2(const float* __restrict__ lat,
                                              __hip_bfloat16* __restrict__ s2) {
    int idx = blockIdx.x * 256 + threadIdx.x;  // < 4,194,304
    int ow = idx & 31;
    int oh = (idx >> 5) & 31;
    int u  = idx >> 10;  // n*CIN + c
    const float* src = lat + (size_t)u * HW;
    const float fk[4] = {0.125f, 0.375f, 0.375f, 0.125f};
    float acc = 0.f;
    #pragma unroll
    for (int i = 0; i < 4; ++i) {
        int r = 2 * oh + i - 1;
        if (r < 0 || r >= H_) continue;
        #pragma unroll
        for (int j = 0; j < 4; ++j) {
            int c = 2 * ow + j - 1;
            if (c < 0 || c >= W_) continue;
            acc += fk[i] * fk[j] * src[r * W_ + c];
        }
    }
    s2[idx] = f2bf(acc);
}

// ---------------------------------------------------------------------------
// Kernel 4: out = act(conv1x1(s2, w_skip*g1))  (WRITES d_out)
// Block: 256 thr over pixels; 4 co per thread. Grid = 16*128*4 = 8192.
// ---------------------------------------------------------------------------
__global__ __launch_bounds__(256) void k_skip(const __hip_bfloat16* __restrict__ s2,
                                              const float* __restrict__ wskip,
                                              float* __restrict__ out) {
    int b   = blockIdx.x;
    int p   = (b & 3) * 256 + threadIdx.x;   // pixel within 32x32
    int co0 = ((b >> 2) & 127) * 4;
    int n   = b >> 9;

    const __hip_bfloat16* sp = s2 + (size_t)(n * CIN) * OHW + p;
    const float* wp = wskip + (size_t)co0 * CIN;

    float a0 = 0.f, a1 = 0.f, a2 = 0.f, a3 = 0.f;
    for (int ci = 0; ci < CIN; ++ci) {
        float v = bf2f(sp[(size_t)ci * OHW]);
        a0 += v * wp[ci];
        a1 += v * wp[CIN + ci];
        a2 += v * wp[2 * CIN + ci];
        a3 += v * wp[3 * CIN + ci];
    }
    size_t ob = ((size_t)(n * COUT + co0)) * OHW + p;
    out[ob]           = actf(a0 * G1);
    out[ob + OHW]     = actf(a1 * G1);
    out[ob + 2 * OHW] = actf(a2 * G1);
    out[ob + 3 * OHW] = actf(a3 * G1);
}

// ---------------------------------------------------------------------------
// Kernel 5: out += act(conv3x3(xf, w_down*g3, stride=2, pad=0)) (ACCUMULATES)
// 2*oh+kh in [0,64] and 2*ow+kw in [0,64] always valid on the 65x65 input.
// Block: 256 thr over pixels; 4 co per thread. Grid = 16*128*4 = 8192.
// ---------------------------------------------------------------------------
__global__ __launch_bounds__(256) void k_down(const __hip_bfloat16* __restrict__ xf,
                                              const float* __restrict__ wdown,
                                              float* __restrict__ out) {
    int b   = blockIdx.x;
    int p   = (b & 3) * 256 + threadIdx.x;
    int oh  = p >> 5, ow = p & 31;
    int co0 = ((b >> 2) & 127) * 4;
    int n   = b >> 9;

    const __hip_bfloat16* xb = xf + (size_t)(n * CIN) * HFF + (2 * oh) * HF + 2 * ow;
    const float* wb = wdown + (size_t)co0 * (CIN * 9);

    float a0 = 0.f, a1 = 0.f, a2 = 0.f, a3 = 0.f;
    for (int ci = 0; ci < CIN; ++ci) {
        const __hip_bfloat16* xc = xb + (size_t)ci * HFF;
        const float* w0 = wb + ci * 9;
        const float* w1 = w0 + CIN * 9;
        const float* w2 = w1 + CIN * 9;
        const float* w3 = w2 + CIN * 9;
        #pragma unroll
        for (int kh = 0; kh < 3; ++kh) {
            float v0 = bf2f(xc[kh * HF + 0]);
            float v1 = bf2f(xc[kh * HF + 1]);
            float v2 = bf2f(xc[kh * HF + 2]);
            a0 += w0[kh * 3] * v0 + w0[kh * 3 + 1] * v1 + w0[kh * 3 + 2] * v2;
            a1 += w1[kh * 3] * v0 + w1[kh * 3 + 1] * v1 + w1[kh * 3 + 2] * v2;
            a2 += w2[kh * 3] * v0 + w2[kh * 3 + 1] * v1 + w2[kh * 3 + 2] * v2;
            a3 += w3[kh * 3] * v0 + w3[kh * 3 + 1] * v1 + w3[kh * 3 + 2] * v2;
        }
    }
    size_t ob = ((size_t)(n * COUT + co0)) * OHW + p;
    out[ob]           += actf(a0 * G3);
    out[ob + OHW]     += actf(a1 * G3);
    out[ob + 2 * OHW] += actf(a2 * G3);
    out[ob + 3 * OHW] += actf(a3 * G3);
}

// ---------------------------------------------------------------------------
extern "C" void kernel_launch(void* const* d_in, const int* in_sizes, int n_in,
                              void* d_out, int out_size, void* d_ws, size_t ws_size,
                              hipStream_t stream) {
    const float* lat   = (const float*)d_in[0];
    const float* wconv = (const float*)d_in[1];
    const float* wdown = (const float*)d_in[2];
    const float* wskip = (const float*)d_in[3];
    float* out = (float*)d_out;

    // Workspace layout (bf16): x1 [16,256,64,64] | xf [16,256,65,65] | s2 [16,256,32,32]
    __hip_bfloat16* x1 = (__hip_bfloat16*)d_ws;
    __hip_bfloat16* xf = x1 + (size_t)N_ * CIN * HW;   // +16,777,216 elems
    __hip_bfloat16* s2 = xf + (size_t)N_ * CIN * HFF;  // +17,305,600 elems
    // total = 76,554,240 bytes

    hipLaunchKernelGGL(k_conv1, dim3(16384), dim3(256), 0, stream, lat, wconv, x1);
    hipLaunchKernelGGL(k_fir1,  dim3((N_ * CIN * HFF + 255) / 256), dim3(256), 0, stream, x1, xf);
    hipLaunchKernelGGL(k_fir2,  dim3(N_ * CIN * OHW / 256), dim3(256), 0, stream, lat, s2);
    hipLaunchKernelGGL(k_skip,  dim3(8192), dim3(256), 0, stream, s2, wskip, out);
    hipLaunchKernelGGL(k_down,  dim3(8192), dim3(256), 0, stream, xf, wdown, out);
}

// Round 2
// 555.954 us; speedup vs baseline: 14.5955x; 14.5955x over previous
//
#include <hip/hip_runtime.h>
#include <hip/hip_bf16.h>
#include <stdint.h>

// DBlock: N=16, Cin=256, Cout=512, H=W=64
// Strategy: NHWC bf16 + implicit GEMM via mfma_f32_16x16x32_bf16.
//   A (M=co)  = weights [tap][co][ci] bf16, lane reads 8 contiguous ci.
//   B (N=px)  = activations NHWC, lane reads 8 contiguous ci at its own pixel
//               (per-lane addressing handles conv shifts/strides/halo).
//   D: col = lane&15 = px, row = 4*(lane>>4)+reg = co  (verified m89 layout).

typedef __bf16 bf8v __attribute__((ext_vector_type(8)));
typedef float  f4   __attribute__((ext_vector_type(4)));

#define G3F (1.0f / 48.0f)
#define G1F (1.0f / 16.0f)
#define SQRT2F 1.4142135623730951f

__device__ __forceinline__ float actf(float v) {
    return (v > 0.0f ? v : 0.2f * v) * SQRT2F;
}
__device__ __forceinline__ unsigned short f2bu(float f) {
    __hip_bfloat16 h = __float2bfloat16(f);
    return *reinterpret_cast<unsigned short*>(&h);
}
__device__ __forceinline__ bf8v ld8(const __hip_bfloat16* p) {
    return *reinterpret_cast<const bf8v*>(p);
}

// ---------------------------------------------------------------------------
// Prep: lat NCHW fp32 -> xb NHWC bf16 (LDS tile transpose)
// grid: n(16) x h(64) x cichunk(8) = 8192 blocks, 256 thr
// ---------------------------------------------------------------------------
__global__ __launch_bounds__(256) void p_xb(const float* __restrict__ lat,
                                            __hip_bfloat16* __restrict__ xb) {
    __shared__ float tile[32][65];
    int bx = blockIdx.x;
    int cic = bx & 7, h = (bx >> 3) & 63, n = bx >> 9;
    int ci0 = cic * 32;
    int t = threadIdx.x;
    {
        int cir = t >> 3, wq = (t & 7) * 8;
        const float* src = lat + (((size_t)(n * 256 + ci0 + cir) * 64 + h) * 64 + wq);
        float4 v0 = *(const float4*)src;
        float4 v1 = *(const float4*)(src + 4);
        tile[cir][wq + 0] = v0.x; tile[cir][wq + 1] = v0.y;
        tile[cir][wq + 2] = v0.z; tile[cir][wq + 3] = v0.w;
        tile[cir][wq + 4] = v1.x; tile[cir][wq + 5] = v1.y;
        tile[cir][wq + 6] = v1.z; tile[cir][wq + 7] = v1.w;
    }
    __syncthreads();
    {
        int w = t >> 2, c8 = (t & 3) * 8;
        union { uint4 q; unsigned short h8[8]; } pk;
        #pragma unroll
        for (int j = 0; j < 8; ++j) pk.h8[j] = f2bu(tile[c8 + j][w]);
        __hip_bfloat16* dst = xb + (((size_t)(n * 64 + h) * 64 + w) * 256 + ci0 + c8);
        *reinterpret_cast<uint4*>(dst) = pk.q;
    }
}

// ---------------------------------------------------------------------------
// Prep: weight reorders (pre-scaled, bf16)
// ---------------------------------------------------------------------------
__global__ __launch_bounds__(256) void p_wc(const float* __restrict__ w,
                                            __hip_bfloat16* __restrict__ wct) {
    int idx = blockIdx.x * 256 + threadIdx.x;        // 65536
    int co = idx >> 8, ci = idx & 255;
    const float* s = w + (size_t)(co * 256 + ci) * 9;
    #pragma unroll
    for (int t = 0; t < 9; ++t)
        wct[(size_t)(t * 256 + co) * 256 + ci] = __float2bfloat16(s[t] * G3F);
}
__global__ __launch_bounds__(256) void p_wd(const float* __restrict__ w,
                                            __hip_bfloat16* __restrict__ wdt) {
    int idx = blockIdx.x * 256 + threadIdx.x;        // 131072
    int co = idx >> 8, ci = idx & 255;
    const float* s = w + (size_t)(co * 256 + ci) * 9;
    #pragma unroll
    for (int t = 0; t < 9; ++t)
        wdt[(size_t)(t * 512 + co) * 256 + ci] = __float2bfloat16(s[t] * G3F);
}
__global__ __launch_bounds__(256) void p_ws(const float* __restrict__ w,
                                            __hip_bfloat16* __restrict__ wst) {
    int idx = blockIdx.x * 256 + threadIdx.x;        // 131072
    wst[idx] = __float2bfloat16(w[idx] * G1F);
}

// ---------------------------------------------------------------------------
// conv1: x1 = act(conv3x3(xb, wct)) NHWC bf16. M=co(256), N=px(65536), K=2304.
// Tile 128co x 128px (2 rows x 64w of one n). Grid = 512 px-tiles x 2 co-tiles.
// ---------------------------------------------------------------------------
__global__ __launch_bounds__(256) void k_conv1m(const __hip_bfloat16* __restrict__ xb,
                                                const __hip_bfloat16* __restrict__ wct,
                                                __hip_bfloat16* __restrict__ x1) {
    const int lane = threadIdx.x & 63;
    const int wid  = threadIdx.x >> 6;
    const int wr = wid >> 1, wcn = wid & 1;
    const int l15 = lane & 15, g = lane >> 4;

    int bx  = blockIdx.x;
    int pxt = bx & 511, cot = bx >> 9;
    int n = pxt >> 5, h0 = (pxt & 31) * 2;
    int co0 = cot * 128 + wr * 64;
    size_t nb = (size_t)n * 4096 * 256;

    f4 acc[4][4];
    #pragma unroll
    for (int m = 0; m < 4; ++m)
        #pragma unroll
        for (int nf = 0; nf < 4; ++nf)
            #pragma unroll
            for (int e = 0; e < 4; ++e) acc[m][nf][e] = 0.0f;

    for (int kh = 0; kh < 3; ++kh) {
        int r = h0 + wcn + kh - 1;
        bool rok = (r >= 0) && (r < 64);
        for (int kw = 0; kw < 3; ++kw) {
            bool bok[4]; int boff[4];
            #pragma unroll
            for (int nf = 0; nf < 4; ++nf) {
                int c = nf * 16 + l15 + kw - 1;
                bok[nf]  = rok && (c >= 0) && (c < 64);
                boff[nf] = bok[nf] ? ((r * 64 + c) * 256 + 8 * g) : 0;
            }
            const __hip_bfloat16* wT = wct + ((size_t)((kh * 3 + kw) * 256 + co0)) * 256;
            for (int ci0 = 0; ci0 < 256; ci0 += 32) {
                bf8v a_[4], b_[4];
                #pragma unroll
                for (int m = 0; m < 4; ++m)
                    a_[m] = ld8(wT + (m * 16 + l15) * 256 + ci0 + 8 * g);
                #pragma unroll
                for (int nf = 0; nf < 4; ++nf) {
                    bf8v v;
                    #pragma unroll
                    for (int e = 0; e < 8; ++e) v[e] = (__bf16)0.0f;
                    if (bok[nf]) v = ld8(xb + nb + (size_t)boff[nf] + ci0);
                    b_[nf] = v;
                }
                #pragma unroll
                for (int m = 0; m < 4; ++m)
                    #pragma unroll
                    for (int nf = 0; nf < 4; ++nf)
                        acc[m][nf] = __builtin_amdgcn_mfma_f32_16x16x32_bf16(
                            a_[m], b_[nf], acc[m][nf], 0, 0, 0);
            }
        }
    }
    // epilogue: act -> bf16 NHWC. Lane: px=(nf,l15), 4 consecutive co per frag.
    int hh = h0 + wcn;
    #pragma unroll
    for (int m = 0; m < 4; ++m)
        #pragma unroll
        for (int nf = 0; nf < 4; ++nf) {
            f4 v = acc[m][nf];
            int w = nf * 16 + l15;
            int co = co0 + m * 16 + 4 * g;
            union { unsigned long long u; unsigned short h4[4]; } pk;
            #pragma unroll
            for (int r4 = 0; r4 < 4; ++r4) pk.h4[r4] = f2bu(actf(v[r4]));
            *reinterpret_cast<unsigned long long*>(
                x1 + nb + (size_t)(hh * 64 + w) * 256 + co) = pk.u;
        }
}

// ---------------------------------------------------------------------------
// fir1: xf = FIR4x4(x1, pad=2) NHWC bf16 [16,65,65,256]
// thread = (n, oh, ow, ci8). grid = 8450 x 256.
// ---------------------------------------------------------------------------
__global__ __launch_bounds__(256) void k_fir1(const __hip_bfloat16* __restrict__ x1,
                                              __hip_bfloat16* __restrict__ xf) {
    int idx = blockIdx.x * 256 + threadIdx.x;  // 16*65*65*32 = 2,163,200
    int c8 = idx & 31; int rest = idx >> 5;
    int ow = rest % 65; rest /= 65;
    int oh = rest % 65; int n = rest / 65;
    int ci = c8 * 8;
    const float fk[4] = {0.125f, 0.375f, 0.375f, 0.125f};
    float a8[8];
    #pragma unroll
    for (int e = 0; e < 8; ++e) a8[e] = 0.0f;
    #pragma unroll
    for (int i = 0; i < 4; ++i) {
        int r = oh + i - 2;
        if (r < 0 || r >= 64) continue;
        #pragma unroll
        for (int j = 0; j < 4; ++j) {
            int c = ow + j - 2;
            if (c < 0 || c >= 64) continue;
            bf8v v = ld8(x1 + ((size_t)(n * 4096) + r * 64 + c) * 256 + ci);
            float fw = fk[i] * fk[j];
            #pragma unroll
            for (int e = 0; e < 8; ++e) a8[e] += fw * (float)v[e];
        }
    }
    union { uint4 q; unsigned short h8[8]; } pk;
    #pragma unroll
    for (int e = 0; e < 8; ++e) pk.h8[e] = f2bu(a8[e]);
    *reinterpret_cast<uint4*>(xf + ((size_t)n * 4225 + oh * 65 + ow) * 256 + ci) = pk.q;
}

// ---------------------------------------------------------------------------
// skip: out = act(conv1x1(FIR_down2(xb), wst)). WRITES d_out (fp32 NCHW).
// M=co(512), N=px(16384: 32x32 per n), K=256. FIR fused into B-frag build.
// Tile 128co x 128px (4 rows x 32). Grid = 128 px-tiles x 4 co-tiles.
// ---------------------------------------------------------------------------
__global__ __launch_bounds__(256) void k_skipm(const __hip_bfloat16* __restrict__ xb,
                                               const __hip_bfloat16* __restrict__ wst,
                                               float* __restrict__ out) {
    const int lane = threadIdx.x & 63;
    const int wid  = threadIdx.x >> 6;
    const int wr = wid >> 1, wcn = wid & 1;
    const int l15 = lane & 15, g = lane >> 4;

    int bx  = blockIdx.x;
    int pxt = bx & 127, cot = bx >> 7;
    int n = pxt >> 3, oh0 = (pxt & 7) * 4;
    int co0 = cot * 128 + wr * 64;
    size_t nb = (size_t)n * 4096 * 256;
    const float fk[4] = {0.125f, 0.375f, 0.375f, 0.125f};

    f4 acc[4][4];
    #pragma unroll
    for (int m = 0; m < 4; ++m)
        #pragma unroll
        for (int nf = 0; nf < 4; ++nf)
            #pragma unroll
            for (int e = 0; e < 4; ++e) acc[m][nf][e] = 0.0f;

    for (int ci0 = 0; ci0 < 256; ci0 += 32) {
        bf8v b_[4];
        #pragma unroll
        for (int nf = 0; nf < 4; ++nf) {
            int oh = oh0 + wcn * 2 + (nf >> 1);
            int ow = (nf & 1) * 16 + l15;
            float a8[8];
            #pragma unroll
            for (int e = 0; e < 8; ++e) a8[e] = 0.0f;
            #pragma unroll
            for (int i = 0; i < 4; ++i) {
                int rr = 2 * oh + i - 1;
                if (rr < 0 || rr >= 64) continue;
                #pragma unroll
                for (int j = 0; j < 4; ++j) {
                    int cc = 2 * ow + j - 1;
                    if (cc >= 0 && cc < 64) {
                        bf8v x = ld8(xb + nb + (size_t)((rr * 64 + cc) * 256 + ci0 + 8 * g));
                        float fw = fk[i] * fk[j];
                        #pragma unroll
                        for (int e = 0; e < 8; ++e) a8[e] += fw * (float)x[e];
                    }
                }
            }
            bf8v bb;
            #pragma unroll
            for (int e = 0; e < 8; ++e) bb[e] = (__bf16)a8[e];
            b_[nf] = bb;
        }
        bf8v a_[4];
        #pragma unroll
        for (int m = 0; m < 4; ++m)
            a_[m] = ld8(wst + (size_t)(co0 + m * 16 + l15) * 256 + ci0 + 8 * g);
        #pragma unroll
        for (int m = 0; m < 4; ++m)
            #pragma unroll
            for (int nf = 0; nf < 4; ++nf)
                acc[m][nf] = __builtin_amdgcn_mfma_f32_16x16x32_bf16(
                    a_[m], b_[nf], acc[m][nf], 0, 0, 0);
    }
    #pragma unroll
    for (int m = 0; m < 4; ++m)
        #pragma unroll
        for (int nf = 0; nf < 4; ++nf) {
            f4 v = acc[m][nf];
            int oh = oh0 + wcn * 2 + (nf >> 1);
            int ow = (nf & 1) * 16 + l15;
            int cobase = co0 + m * 16 + 4 * g;
            #pragma unroll
            for (int r4 = 0; r4 < 4; ++r4) {
                size_t oi = ((size_t)(n * 512 + cobase + r4)) * 1024 + oh * 32 + ow;
                out[oi] = actf(v[r4]);
            }
        }
}

// ---------------------------------------------------------------------------
// down: out += act(conv3x3_s2(xf, wdt)). ACCUMULATES into d_out.
// M=co(512), N=px(16384), K=2304. Input xf NHWC [65,65,256]. No predication.
// ---------------------------------------------------------------------------
__global__ __launch_bounds__(256) void k_downm(const __hip_bfloat16* __restrict__ xf,
                                               const __hip_bfloat16* __restrict__ wdt,
                                               float* __restrict__ out) {
    const int lane = threadIdx.x & 63;
    const int wid  = threadIdx.x >> 6;
    const int wr = wid >> 1, wcn = wid & 1;
    const int l15 = lane & 15, g = lane >> 4;

    int bx  = blockIdx.x;
    int pxt = bx & 127, cot = bx >> 7;
    int n = pxt >> 3, oh0 = (pxt & 7) * 4;
    int co0 = cot * 128 + wr * 64;
    size_t nb = (size_t)n * 4225 * 256;

    f4 acc[4][4];
    #pragma unroll
    for (int m = 0; m < 4; ++m)
        #pragma unroll
        for (int nf = 0; nf < 4; ++nf)
            #pragma unroll
            for (int e = 0; e < 4; ++e) acc[m][nf][e] = 0.0f;

    for (int kh = 0; kh < 3; ++kh) {
        for (int kw = 0; kw < 3; ++kw) {
            int boff[4];
            #pragma unroll
            for (int nf = 0; nf < 4; ++nf) {
                int oh = oh0 + wcn * 2 + (nf >> 1);
                int ow = (nf & 1) * 16 + l15;
                int rr = 2 * oh + kh, cc = 2 * ow + kw;
                boff[nf] = (rr * 65 + cc) * 256 + 8 * g;
            }
            const __hip_bfloat16* wT = wdt + ((size_t)((kh * 3 + kw) * 512 + co0)) * 256;
            for (int ci0 = 0; ci0 < 256; ci0 += 32) {
                bf8v a_[4], b_[4];
                #pragma unroll
                for (int m = 0; m < 4; ++m)
                    a_[m] = ld8(wT + (m * 16 + l15) * 256 + ci0 + 8 * g);
                #pragma unroll
                for (int nf = 0; nf < 4; ++nf)
                    b_[nf] = ld8(xf + nb + (size_t)boff[nf] + ci0);
                #pragma unroll
                for (int m = 0; m < 4; ++m)
                    #pragma unroll
                    for (int nf = 0; nf < 4; ++nf)
                        acc[m][nf] = __builtin_amdgcn_mfma_f32_16x16x32_bf16(
                            a_[m], b_[nf], acc[m][nf], 0, 0, 0);
            }
        }
    }
    #pragma unroll
    for (int m = 0; m < 4; ++m)
        #pragma unroll
        for (int nf = 0; nf < 4; ++nf) {
            f4 v = acc[m][nf];
            int oh = oh0 + wcn * 2 + (nf >> 1);
            int ow = (nf & 1) * 16 + l15;
            int cobase = co0 + m * 16 + 4 * g;
            #pragma unroll
            for (int r4 = 0; r4 < 4; ++r4) {
                size_t oi = ((size_t)(n * 512 + cobase + r4)) * 1024 + oh * 32 + ow;
                out[oi] += actf(v[r4]);
            }
        }
}

// ---------------------------------------------------------------------------
extern "C" void kernel_launch(void* const* d_in, const int* in_sizes, int n_in,
                              void* d_out, int out_size, void* d_ws, size_t ws_size,
                              hipStream_t stream) {
    const float* lat   = (const float*)d_in[0];
    const float* wconv = (const float*)d_in[1];
    const float* wdown = (const float*)d_in[2];
    const float* wskip = (const float*)d_in[3];
    float* out = (float*)d_out;

    // ws layout (bytes):
    //   region0 [0, 34,611,200): xb (33.55MB, NHWC bf16 input) then OVERWRITTEN
    //           by xf (34.61MB) after conv1+skip are done reading xb.
    //   x1  at 34,611,200  (33,554,432 B)
    //   wct at 68,165,632  ( 1,179,648 B)
    //   wdt at 69,345,280  ( 2,359,296 B)
    //   wst at 71,704,576  (   262,144 B)   total 71,966,720 B
    char* base = (char*)d_ws;
    __hip_bfloat16* xb  = (__hip_bfloat16*)base;
    __hip_bfloat16* xf  = (__hip_bfloat16*)base;   // overlays xb (safe: see order)
    __hip_bfloat16* x1  = (__hip_bfloat16*)(base + 34611200);
    __hip_bfloat16* wct = (__hip_bfloat16*)(base + 68165632);
    __hip_bfloat16* wdt = (__hip_bfloat16*)(base + 69345280);
    __hip_bfloat16* wst = (__hip_bfloat16*)(base + 71704576);

    hipLaunchKernelGGL(p_xb,    dim3(8192), dim3(256), 0, stream, lat,   xb);
    hipLaunchKernelGGL(p_wc,    dim3(256),  dim3(256), 0, stream, wconv, wct);
    hipLaunchKernelGGL(p_wd,    dim3(512),  dim3(256), 0, stream, wdown, wdt);
    hipLaunchKernelGGL(p_ws,    dim3(512),  dim3(256), 0, stream, wskip, wst);
    hipLaunchKernelGGL(k_conv1m, dim3(1024), dim3(256), 0, stream, xb, wct, x1);
    hipLaunchKernelGGL(k_skipm,  dim3(512),  dim3(256), 0, stream, xb, wst, out);
    hipLaunchKernelGGL(k_fir1,   dim3(8450), dim3(256), 0, stream, x1, xf);
    hipLaunchKernelGGL(k_downm,  dim3(512),  dim3(256), 0, stream, xf, wdt, out);
}

// Round 3
// 410.659 us; speedup vs baseline: 19.7595x; 1.3538x over previous
//
#include <hip/hip_runtime.h>
#include <hip/hip_bf16.h>
#include <stdint.h>

// DBlock: N=16, Cin=256, Cout=512, H=W=64
// NHWC bf16 implicit GEMM on mfma_f32_16x16x32_bf16, LDS-staged inputs
// (global_load_lds w=16, XOR-swizzled), fragment-linear weights.

typedef __bf16 bf8v __attribute__((ext_vector_type(8)));
typedef float  f4   __attribute__((ext_vector_type(4)));

#define G3F (1.0f / 48.0f)
#define G1F (1.0f / 16.0f)
#define SQRT2F 1.4142135623730951f

__device__ __forceinline__ float actf(float v) {
    return (v > 0.0f ? v : 0.2f * v) * SQRT2F;
}
__device__ __forceinline__ unsigned short f2bu(float f) {
    __hip_bfloat16 h = __float2bfloat16(f);
    return *reinterpret_cast<unsigned short*>(&h);
}
__device__ __forceinline__ bf8v ld8(const __hip_bfloat16* p) {
    return *reinterpret_cast<const bf8v*>(p);
}
// async global->LDS, 16B per lane, dest = base + lane*16 (HW-fixed)
__device__ __forceinline__ void llds16(const __hip_bfloat16* g, void* l) {
    __builtin_amdgcn_global_load_lds(
        (const __attribute__((address_space(1))) unsigned int*)g,
        (__attribute__((address_space(3))) unsigned int*)l, 16, 0, 0);
}

// ---------------------------------------------------------------------------
// Prep: lat NCHW fp32 -> xb NHWC bf16
// ---------------------------------------------------------------------------
__global__ __launch_bounds__(256) void p_xb(const float* __restrict__ lat,
                                            __hip_bfloat16* __restrict__ xb) {
    __shared__ float tile[32][65];
    int bx = blockIdx.x;
    int cic = bx & 7, h = (bx >> 3) & 63, n = bx >> 9;
    int ci0 = cic * 32;
    int t = threadIdx.x;
    {
        int cir = t >> 3, wq = (t & 7) * 8;
        const float* src = lat + (((size_t)(n * 256 + ci0 + cir) * 64 + h) * 64 + wq);
        float4 v0 = *(const float4*)src;
        float4 v1 = *(const float4*)(src + 4);
        tile[cir][wq + 0] = v0.x; tile[cir][wq + 1] = v0.y;
        tile[cir][wq + 2] = v0.z; tile[cir][wq + 3] = v0.w;
        tile[cir][wq + 4] = v1.x; tile[cir][wq + 5] = v1.y;
        tile[cir][wq + 6] = v1.z; tile[cir][wq + 7] = v1.w;
    }
    __syncthreads();
    {
        int w = t >> 2, c8 = (t & 3) * 8;
        union { uint4 q; unsigned short h8[8]; } pk;
        #pragma unroll
        for (int j = 0; j < 8; ++j) pk.h8[j] = f2bu(tile[c8 + j][w]);
        __hip_bfloat16* dst = xb + (((size_t)(n * 64 + h) * 64 + w) * 256 + ci0 + c8);
        *reinterpret_cast<uint4*>(dst) = pk.q;
    }
}

// ---------------------------------------------------------------------------
// Preps: weights -> fragment-linear bf16 (one contiguous 1KB per wave A-load)
// wA[((t*8+q)*16 + co16)*512 + lane*8 ..] : co = co16*16+(l&15), ci = q*32+(l>>4)*8
// ---------------------------------------------------------------------------
__global__ __launch_bounds__(256) void p_wA(const float* __restrict__ w,
                                            __hip_bfloat16* __restrict__ wA) {
    int idx = blockIdx.x * 256 + threadIdx.x;       // 73728
    int lane = idx & 63;
    int co16 = (idx >> 6) & 15;
    int q    = (idx >> 10) & 7;
    int t    = idx >> 13;                           // 0..8
    int co = co16 * 16 + (lane & 15);
    int ci = q * 32 + (lane >> 4) * 8;
    union { uint4 v; unsigned short h8[8]; } pk;
    #pragma unroll
    for (int e = 0; e < 8; ++e)
        pk.h8[e] = f2bu(w[(size_t)(co * 256 + ci + e) * 9 + t] * G3F);
    *reinterpret_cast<uint4*>(wA + (size_t)idx * 8) = pk.v;
}
__global__ __launch_bounds__(256) void p_wD(const float* __restrict__ w,
                                            __hip_bfloat16* __restrict__ wD) {
    int idx = blockIdx.x * 256 + threadIdx.x;       // 147456
    int lane = idx & 63;
    int co16 = (idx >> 6) & 31;
    int q    = (idx >> 11) & 7;
    int t    = idx >> 14;                           // 0..8
    int co = co16 * 16 + (lane & 15);
    int ci = q * 32 + (lane >> 4) * 8;
    union { uint4 v; unsigned short h8[8]; } pk;
    #pragma unroll
    for (int e = 0; e < 8; ++e)
        pk.h8[e] = f2bu(w[(size_t)(co * 256 + ci + e) * 9 + t] * G3F);
    *reinterpret_cast<uint4*>(wD + (size_t)idx * 8) = pk.v;
}
__global__ __launch_bounds__(256) void p_ws(const float* __restrict__ w,
                                            __hip_bfloat16* __restrict__ wst) {
    int idx = blockIdx.x * 256 + threadIdx.x;       // 131072
    wst[idx] = __float2bfloat16(w[idx] * G1F);
}

// ---------------------------------------------------------------------------
// conv1: x1 = act(conv3x3(xb)) NHWC. Block: 4 waves, 256co x 128px (2 rows).
// LDS: 4 input rows x 64w x 16 c8slots x 16B = 64KB, staged per ci-half.
// Swizzle: data c8 stored at slot c8s = c8 ^ (w&7)  (read & source both sides).
// Grid = 512 (n x h0-tile). 1152 MFMA/wave per barrier phase.
// ---------------------------------------------------------------------------
__global__ __launch_bounds__(256, 2) void k_conv1s(const __hip_bfloat16* __restrict__ xb,
                                                   const __hip_bfloat16* __restrict__ wA,
                                                   __hip_bfloat16* __restrict__ x1) {
    __shared__ uint4 sm4[4096];                      // 65536 B
    char* smc = (char*)sm4;
    const int tid  = threadIdx.x;
    const int lane = tid & 63;
    const int wid  = tid >> 6;
    const int l15  = lane & 15, g = lane >> 4;

    const int bx = blockIdx.x;
    const int h0 = (bx & 31) * 2;
    const int n  = bx >> 5;
    const size_t nb = (size_t)n * 4096 * 256;
    const char* wAc = (const char*)wA;

    f4 acc[4][8];
    #pragma unroll
    for (int m = 0; m < 4; ++m)
        #pragma unroll
        for (int nf = 0; nf < 8; ++nf)
            #pragma unroll
            for (int e = 0; e < 4; ++e) acc[m][nf][e] = 0.0f;

    const bf8v zero8 = {};

    #pragma unroll 1
    for (int half = 0; half < 2; ++half) {
        if (half) __syncthreads();                   // protect LDS readers
        {   // wave `wid` stages input row r = h0 + wid - 1 (16 x 1KB loads)
            int r = h0 + wid - 1;
            if ((unsigned)r < 64u) {
                int rc = r;
                #pragma unroll
                for (int i = 0; i < 16; ++i) {
                    int slot = i * 64 + lane;
                    int w  = slot >> 4;
                    int c8 = (slot & 15) ^ (w & 7);  // inverse swizzle on source
                    const __hip_bfloat16* src =
                        xb + nb + ((size_t)(rc * 64 + w) * 256 + half * 128 + c8 * 8);
                    llds16(src, smc + wid * 16384 + i * 1024);
                }
            }
        }
        __syncthreads();

        #pragma unroll 1
        for (int kh = 0; kh < 3; ++kh) {
            const bool bad0 = ((unsigned)(h0 + kh - 1) >= 64u);  // nf 0..3 row
            const bool bad1 = ((unsigned)(h0 + kh)     >= 64u);  // nf 4..7 row
            #pragma unroll
            for (int kw = 0; kw < 3; ++kw) {
                #pragma unroll
                for (int qq = 0; qq < 4; ++qq) {
                    const int c8 = qq * 4 + g;       // ci slot within half
                    bf8v b_[8];
                    #pragma unroll
                    for (int nf = 0; nf < 8; ++nf) {
                        int w  = (nf & 3) * 16 + l15;
                        int wc = w + kw - 1;
                        int wcc = wc < 0 ? 0 : (wc > 63 ? 63 : wc);
                        int off = ((nf >> 2) + kh) * 16384 +
                                  (wcc * 16 + (c8 ^ (wcc & 7))) * 16;
                        bf8v v = *(const bf8v*)(smc + off);
                        bool bad = (nf < 4 ? bad0 : bad1) ||
                                   (kw == 0 && (nf & 3) == 0 && l15 == 0) ||
                                   (kw == 2 && (nf & 3) == 3 && l15 == 15);
                        b_[nf] = bad ? zero8 : v;
                    }
                    const int q = half * 4 + qq;
                    #pragma unroll
                    for (int m = 0; m < 4; ++m) {
                        bf8v a = *(const bf8v*)(wAc +
                            ((size_t)(((kh * 3 + kw) * 8 + q) * 16 + wid * 4 + m) << 10) +
                            (lane << 4));
                        #pragma unroll
                        for (int nf = 0; nf < 8; ++nf)
                            acc[m][nf] = __builtin_amdgcn_mfma_f32_16x16x32_bf16(
                                a, b_[nf], acc[m][nf], 0, 0, 0);
                    }
                }
            }
        }
    }

    // epilogue: act -> bf16 NHWC (8B store: 4 consecutive co)
    #pragma unroll
    for (int m = 0; m < 4; ++m)
        #pragma unroll
        for (int nf = 0; nf < 8; ++nf) {
            f4 v = acc[m][nf];
            int hh = h0 + (nf >> 2);
            int w  = (nf & 3) * 16 + l15;
            int co = wid * 64 + m * 16 + 4 * g;
            union { unsigned long long u; unsigned short h4[4]; } pk;
            #pragma unroll
            for (int r4 = 0; r4 < 4; ++r4) pk.h4[r4] = f2bu(actf(v[r4]));
            *reinterpret_cast<unsigned long long*>(
                x1 + nb + (size_t)(hh * 64 + w) * 256 + co) = pk.u;
        }
}

// ---------------------------------------------------------------------------
// fir1: xf = FIR4x4(x1, pad=2) NHWC bf16 [16,65,65,256]
// ---------------------------------------------------------------------------
__global__ __launch_bounds__(256) void k_fir1(const __hip_bfloat16* __restrict__ x1,
                                              __hip_bfloat16* __restrict__ xf) {
    int idx = blockIdx.x * 256 + threadIdx.x;  // 2,163,200
    int c8 = idx & 31; int rest = idx >> 5;
    int ow = rest % 65; rest /= 65;
    int oh = rest % 65; int n = rest / 65;
    int ci = c8 * 8;
    const float fk[4] = {0.125f, 0.375f, 0.375f, 0.125f};
    float a8[8];
    #pragma unroll
    for (int e = 0; e < 8; ++e) a8[e] = 0.0f;
    #pragma unroll
    for (int i = 0; i < 4; ++i) {
        int r = oh + i - 2;
        if (r < 0 || r >= 64) continue;
        #pragma unroll
        for (int j = 0; j < 4; ++j) {
            int c = ow + j - 2;
            if (c < 0 || c >= 64) continue;
            bf8v v = ld8(x1 + ((size_t)(n * 4096) + r * 64 + c) * 256 + ci);
            float fw = fk[i] * fk[j];
            #pragma unroll
            for (int e = 0; e < 8; ++e) a8[e] += fw * (float)v[e];
        }
    }
    union { uint4 q; unsigned short h8[8]; } pk;
    #pragma unroll
    for (int e = 0; e < 8; ++e) pk.h8[e] = f2bu(a8[e]);
    *reinterpret_cast<uint4*>(xf + ((size_t)n * 4225 + oh * 65 + ow) * 256 + ci) = pk.q;
}

// ---------------------------------------------------------------------------
// skip: out = act(conv1x1(FIR_down2(xb))). WRITES d_out (fp32 NCHW).
// ---------------------------------------------------------------------------
__global__ __launch_bounds__(256) void k_skipm(const __hip_bfloat16* __restrict__ xb,
                                               const __hip_bfloat16* __restrict__ wst,
                                               float* __restrict__ out) {
    const int lane = threadIdx.x & 63;
    const int wid  = threadIdx.x >> 6;
    const int wr = wid >> 1, wcn = wid & 1;
    const int l15 = lane & 15, g = lane >> 4;

    int bx  = blockIdx.x;
    int pxt = bx & 127, cot = bx >> 7;
    int n = pxt >> 3, oh0 = (pxt & 7) * 4;
    int co0 = cot * 128 + wr * 64;
    size_t nb = (size_t)n * 4096 * 256;
    const float fk[4] = {0.125f, 0.375f, 0.375f, 0.125f};

    f4 acc[4][4];
    #pragma unroll
    for (int m = 0; m < 4; ++m)
        #pragma unroll
        for (int nf = 0; nf < 4; ++nf)
            #pragma unroll
            for (int e = 0; e < 4; ++e) acc[m][nf][e] = 0.0f;

    for (int ci0 = 0; ci0 < 256; ci0 += 32) {
        bf8v b_[4];
        #pragma unroll
        for (int nf = 0; nf < 4; ++nf) {
            int oh = oh0 + wcn * 2 + (nf >> 1);
            int ow = (nf & 1) * 16 + l15;
            float a8[8];
            #pragma unroll
            for (int e = 0; e < 8; ++e) a8[e] = 0.0f;
            #pragma unroll
            for (int i = 0; i < 4; ++i) {
                int rr = 2 * oh + i - 1;
                if (rr < 0 || rr >= 64) continue;
                #pragma unroll
                for (int j = 0; j < 4; ++j) {
                    int cc = 2 * ow + j - 1;
                    if (cc >= 0 && cc < 64) {
                        bf8v x = ld8(xb + nb + (size_t)((rr * 64 + cc) * 256 + ci0 + 8 * g));
                        float fw = fk[i] * fk[j];
                        #pragma unroll
                        for (int e = 0; e < 8; ++e) a8[e] += fw * (float)x[e];
                    }
                }
            }
            bf8v bb;
            #pragma unroll
            for (int e = 0; e < 8; ++e) bb[e] = (__bf16)a8[e];
            b_[nf] = bb;
        }
        bf8v a_[4];
        #pragma unroll
        for (int m = 0; m < 4; ++m)
            a_[m] = ld8(wst + (size_t)(co0 + m * 16 + l15) * 256 + ci0 + 8 * g);
        #pragma unroll
        for (int m = 0; m < 4; ++m)
            #pragma unroll
            for (int nf = 0; nf < 4; ++nf)
                acc[m][nf] = __builtin_amdgcn_mfma_f32_16x16x32_bf16(
                    a_[m], b_[nf], acc[m][nf], 0, 0, 0);
    }
    #pragma unroll
    for (int m = 0; m < 4; ++m)
        #pragma unroll
        for (int nf = 0; nf < 4; ++nf) {
            f4 v = acc[m][nf];
            int oh = oh0 + wcn * 2 + (nf >> 1);
            int ow = (nf & 1) * 16 + l15;
            int cobase = co0 + m * 16 + 4 * g;
            #pragma unroll
            for (int r4 = 0; r4 < 4; ++r4) {
                size_t oi = ((size_t)(n * 512 + cobase + r4)) * 1024 + oh * 32 + ow;
                out[oi] = actf(v[r4]);
            }
        }
}

// ---------------------------------------------------------------------------
// down: out += act(conv3x3_s2(xf)). Block: 4 waves, 256co x 64px (2 orows x 32).
// LDS: 5 input rows x 65 physw x 8 c8slots x 16B = 41600B (+pad to 41984).
// No halo (all reads valid). Swizzle key = (physw>>1)&7. Grid = 512.
// ---------------------------------------------------------------------------
__global__ __launch_bounds__(256, 2) void k_downs(const __hip_bfloat16* __restrict__ xf,
                                                  const __hip_bfloat16* __restrict__ wD,
                                                  float* __restrict__ out) {
    __shared__ uint4 smd[2624];                      // 41984 B
    char* smc = (char*)smd;
    const int tid  = threadIdx.x;
    const int lane = tid & 63;
    const int wid  = tid >> 6;
    const int l15  = lane & 15, g = lane >> 4;

    const int bx  = blockIdx.x;
    const int cot = bx & 1;
    const int oht = (bx >> 1) & 15;
    const int n   = bx >> 5;
    const int r0  = oht * 4;                         // input row base
    const size_t nb = (size_t)n * 4225 * 256;
    const char* wDc = (const char*)wD;
    const int co16b = cot * 16 + wid * 4;

    f4 acc[4][4];
    #pragma unroll
    for (int m = 0; m < 4; ++m)
        #pragma unroll
        for (int nf = 0; nf < 4; ++nf)
            #pragma unroll
            for (int e = 0; e < 4; ++e) acc[m][nf][e] = 0.0f;

    #pragma unroll 1
    for (int ch = 0; ch < 4; ++ch) {                 // 64-ci chunks
        if (ch) __syncthreads();
        // stage 5 rows x 65 w x 64 ci = 2600 slots; 41 wave-loads round-robin
        for (int li = wid; li < 41; li += 4) {
            int slot0 = li * 64 + lane;
            int slot  = slot0 > 2599 ? 2599 : slot0;
            int row = slot / 520;
            int rem = slot - row * 520;
            int physw = rem >> 3;
            int c8 = (rem & 7) ^ ((physw >> 1) & 7); // inverse swizzle on source
            const __hip_bfloat16* src = xf + nb +
                ((size_t)((r0 + row) * 65 + physw) * 256 + ch * 64 + c8 * 8);
            llds16(src, smc + li * 1024);
        }
        __syncthreads();

        #pragma unroll 1
        for (int kh = 0; kh < 3; ++kh) {
            #pragma unroll
            for (int kw = 0; kw < 3; ++kw) {
                #pragma unroll
                for (int qq = 0; qq < 2; ++qq) {
                    const int c8 = qq * 4 + g;       // 0..7
                    bf8v b_[4];
                    #pragma unroll
                    for (int nf = 0; nf < 4; ++nf) {
                        int ow = (nf & 1) * 16 + l15;
                        int physw = 2 * ow + kw;
                        int ridx  = 2 * (nf >> 1) + kh;
                        int off = ridx * 8320 +
                                  (physw * 8 + (c8 ^ ((physw >> 1) & 7))) * 16;
                        b_[nf] = *(const bf8v*)(smc + off);
                    }
                    const int q = ch * 2 + qq;
                    #pragma unroll
                    for (int m = 0; m < 4; ++m) {
                        bf8v a = *(const bf8v*)(wDc +
                            ((size_t)(((kh * 3 + kw) * 8 + q) * 32 + co16b + m) << 10) +
                            (lane << 4));
                        #pragma unroll
                        for (int nf = 0; nf < 4; ++nf)
                            acc[m][nf] = __builtin_amdgcn_mfma_f32_16x16x32_bf16(
                                a, b_[nf], acc[m][nf], 0, 0, 0);
                    }
                }
            }
        }
    }

    #pragma unroll
    for (int m = 0; m < 4; ++m)
        #pragma unroll
        for (int nf = 0; nf < 4; ++nf) {
            f4 v = acc[m][nf];
            int oh = oht * 2 + (nf >> 1);
            int ow = (nf & 1) * 16 + l15;
            int cobase = cot * 256 + wid * 64 + m * 16 + 4 * g;
            #pragma unroll
            for (int r4 = 0; r4 < 4; ++r4) {
                size_t oi = ((size_t)(n * 512 + cobase + r4)) * 1024 + oh * 32 + ow;
                out[oi] += actf(v[r4]);
            }
        }
}

// ---------------------------------------------------------------------------
extern "C" void kernel_launch(void* const* d_in, const int* in_sizes, int n_in,
                              void* d_out, int out_size, void* d_ws, size_t ws_size,
                              hipStream_t stream) {
    const float* lat   = (const float*)d_in[0];
    const float* wconv = (const float*)d_in[1];
    const float* wdown = (const float*)d_in[2];
    const float* wskip = (const float*)d_in[3];
    float* out = (float*)d_out;

    // ws layout: region0 [0,34.6MB): xb then xf (overlay; safe by stream order)
    char* base = (char*)d_ws;
    __hip_bfloat16* xb  = (__hip_bfloat16*)base;
    __hip_bfloat16* xf  = (__hip_bfloat16*)base;
    __hip_bfloat16* x1  = (__hip_bfloat16*)(base + 34611200);
    __hip_bfloat16* wA  = (__hip_bfloat16*)(base + 68165632);   // 1,179,648 B
    __hip_bfloat16* wD  = (__hip_bfloat16*)(base + 69345280);   // 2,359,296 B
    __hip_bfloat16* wst = (__hip_bfloat16*)(base + 71704576);   //   262,144 B

    hipLaunchKernelGGL(p_xb,    dim3(8192), dim3(256), 0, stream, lat,   xb);
    hipLaunchKernelGGL(p_wA,    dim3(288),  dim3(256), 0, stream, wconv, wA);
    hipLaunchKernelGGL(p_wD,    dim3(576),  dim3(256), 0, stream, wdown, wD);
    hipLaunchKernelGGL(p_ws,    dim3(512),  dim3(256), 0, stream, wskip, wst);
    hipLaunchKernelGGL(k_conv1s, dim3(512), dim3(256), 0, stream, xb, wA, x1);
    hipLaunchKernelGGL(k_skipm,  dim3(512), dim3(256), 0, stream, xb, wst, out);
    hipLaunchKernelGGL(k_fir1,   dim3(8450), dim3(256), 0, stream, x1, xf);
    hipLaunchKernelGGL(k_downs,  dim3(512), dim3(256), 0, stream, xf, wD, out);
}

// Round 4
// 226.600 us; speedup vs baseline: 35.8094x; 1.8123x over previous
//
#include <hip/hip_runtime.h>
#include <hip/hip_bf16.h>
#include <stdint.h>

// DBlock: N=16, Cin=256, Cout=512, H=W=64
// NHWC bf16 implicit GEMM, mfma_f32_16x16x32_bf16.
// xb padded to [16][64][66][256] (zero cols wp=0,65) -> no w-halo masking.
// conv1/downs: LDS-staged B (global_load_lds w=16, XOR-swizzled), 4 blocks/CU.

typedef __bf16 bf8v __attribute__((ext_vector_type(8)));
typedef float  f4   __attribute__((ext_vector_type(4)));

#define G3F (1.0f / 48.0f)
#define G1F (1.0f / 16.0f)
#define SQRT2F 1.4142135623730951f

__device__ __forceinline__ float actf(float v) {
    return (v > 0.0f ? v : 0.2f * v) * SQRT2F;
}
__device__ __forceinline__ unsigned short f2bu(float f) {
    __hip_bfloat16 h = __float2bfloat16(f);
    return *reinterpret_cast<unsigned short*>(&h);
}
__device__ __forceinline__ bf8v ld8(const __hip_bfloat16* p) {
    return *reinterpret_cast<const bf8v*>(p);
}
__device__ __forceinline__ void llds16(const __hip_bfloat16* g, void* l) {
    __builtin_amdgcn_global_load_lds(
        (const __attribute__((address_space(1))) unsigned int*)g,
        (__attribute__((address_space(3))) unsigned int*)l, 16, 0, 0);
}

// ---------------------------------------------------------------------------
// p_pad: zero the two pad columns (wp=0, wp=65) of padded xb
// ---------------------------------------------------------------------------
__global__ __launch_bounds__(256) void p_pad(__hip_bfloat16* __restrict__ xb) {
    int idx = blockIdx.x * 256 + threadIdx.x;       // 65536
    int c8 = idx & 31, side = (idx >> 5) & 1, h = (idx >> 6) & 63, n = idx >> 12;
    int wp = side * 65;
    uint4 z = {0, 0, 0, 0};
    *reinterpret_cast<uint4*>(xb + (((size_t)(n * 64 + h) * 66 + wp) << 8) + c8 * 8) = z;
}

// ---------------------------------------------------------------------------
// p_xb: lat NCHW fp32 -> xb NHWC bf16 padded [16][64][66][256] (writes wp=1..64)
// ---------------------------------------------------------------------------
__global__ __launch_bounds__(256) void p_xb(const float* __restrict__ lat,
                                            __hip_bfloat16* __restrict__ xb) {
    __shared__ float tile[32][65];
    int bx = blockIdx.x;
    int cic = bx & 7, h = (bx >> 3) & 63, n = bx >> 9;
    int ci0 = cic * 32;
    int t = threadIdx.x;
    {
        int cir = t >> 3, wq = (t & 7) * 8;
        const float* src = lat + (((size_t)(n * 256 + ci0 + cir) * 64 + h) * 64 + wq);
        float4 v0 = *(const float4*)src;
        float4 v1 = *(const float4*)(src + 4);
        tile[cir][wq + 0] = v0.x; tile[cir][wq + 1] = v0.y;
        tile[cir][wq + 2] = v0.z; tile[cir][wq + 3] = v0.w;
        tile[cir][wq + 4] = v1.x; tile[cir][wq + 5] = v1.y;
        tile[cir][wq + 6] = v1.z; tile[cir][wq + 7] = v1.w;
    }
    __syncthreads();
    {
        int w = t >> 2, c8 = (t & 3) * 8;
        union { uint4 q; unsigned short h8[8]; } pk;
        #pragma unroll
        for (int j = 0; j < 8; ++j) pk.h8[j] = f2bu(tile[c8 + j][w]);
        __hip_bfloat16* dst = xb + (((size_t)(n * 64 + h) * 66 + (w + 1)) << 8) + ci0 + c8;
        *reinterpret_cast<uint4*>(dst) = pk.q;
    }
}

// ---------------------------------------------------------------------------
// Weight preps: fragment-linear bf16 (1 contiguous KB per wave A-load)
// ---------------------------------------------------------------------------
__global__ __launch_bounds__(256) void p_wA(const float* __restrict__ w,
                                            __hip_bfloat16* __restrict__ wA) {
    int idx = blockIdx.x * 256 + threadIdx.x;       // 73728
    int lane = idx & 63;
    int co16 = (idx >> 6) & 15;
    int q    = (idx >> 10) & 7;
    int t    = idx >> 13;
    int co = co16 * 16 + (lane & 15);
    int ci = q * 32 + (lane >> 4) * 8;
    union { uint4 v; unsigned short h8[8]; } pk;
    #pragma unroll
    for (int e = 0; e < 8; ++e)
        pk.h8[e] = f2bu(w[(size_t)(co * 256 + ci + e) * 9 + t] * G3F);
    *reinterpret_cast<uint4*>(wA + (size_t)idx * 8) = pk.v;
}
__global__ __launch_bounds__(256) void p_wD(const float* __restrict__ w,
                                            __hip_bfloat16* __restrict__ wD) {
    int idx = blockIdx.x * 256 + threadIdx.x;       // 147456
    int lane = idx & 63;
    int co16 = (idx >> 6) & 31;
    int q    = (idx >> 11) & 7;
    int t    = idx >> 14;
    int co = co16 * 16 + (lane & 15);
    int ci = q * 32 + (lane >> 4) * 8;
    union { uint4 v; unsigned short h8[8]; } pk;
    #pragma unroll
    for (int e = 0; e < 8; ++e)
        pk.h8[e] = f2bu(w[(size_t)(co * 256 + ci + e) * 9 + t] * G3F);
    *reinterpret_cast<uint4*>(wD + (size_t)idx * 8) = pk.v;
}
__global__ __launch_bounds__(256) void p_ws(const float* __restrict__ w,
                                            __hip_bfloat16* __restrict__ wst) {
    int idx = blockIdx.x * 256 + threadIdx.x;       // 131072
    wst[idx] = __float2bfloat16(w[idx] * G1F);
}

// ---------------------------------------------------------------------------
// fir2n: s2 = FIR4x4(xb, pad=1, down=2)  NHWC bf16 [16][32][32][256]
// ---------------------------------------------------------------------------
__global__ __launch_bounds__(256) void k_fir2n(const __hip_bfloat16* __restrict__ xb,
                                               __hip_bfloat16* __restrict__ s2) {
    int idx = blockIdx.x * 256 + threadIdx.x;       // 524288
    int c8 = idx & 31, ow = (idx >> 5) & 31, oh = (idx >> 10) & 31, n = idx >> 15;
    const float fk[4] = {0.125f, 0.375f, 0.375f, 0.125f};
    float a8[8];
    #pragma unroll
    for (int e = 0; e < 8; ++e) a8[e] = 0.0f;
    const __hip_bfloat16* src = xb + ((size_t)n * 64 * 66) * 256 + c8 * 8;
    #pragma unroll
    for (int i = 0; i < 4; ++i) {
        int rr = 2 * oh + i - 1;
        if ((unsigned)rr >= 64u) continue;
        #pragma unroll
        for (int j = 0; j < 4; ++j) {
            int wp = 2 * ow + j;                    // padded coord, always valid
            bf8v v = ld8(src + ((size_t)(rr * 66 + wp) << 8));
            float fw = fk[i] * fk[j];
            #pragma unroll
            for (int e = 0; e < 8; ++e) a8[e] += fw * (float)v[e];
        }
    }
    union { uint4 q; unsigned short h8[8]; } pk;
    #pragma unroll
    for (int e = 0; e < 8; ++e) pk.h8[e] = f2bu(a8[e]);
    *reinterpret_cast<uint4*>(s2 + (((size_t)(n * 1024 + oh * 32 + ow)) << 8) + c8 * 8) = pk.q;
}

// ---------------------------------------------------------------------------
// skipg: out = act(conv1x1(s2, wst)). Pure GEMM M=512 N=16384 K=256. WRITES out.
// Block: 4 waves, 128co x 128px; wave 64co x 64px. Grid 512 (XCD-swizzled).
// ---------------------------------------------------------------------------
__global__ __launch_bounds__(256) void k_skipg(const __hip_bfloat16* __restrict__ s2,
                                               const __hip_bfloat16* __restrict__ wst,
                                               float* __restrict__ out) {
    const int lane = threadIdx.x & 63;
    const int wid  = threadIdx.x >> 6;
    const int wr = wid & 1, wc = wid >> 1;
    const int l15 = lane & 15, g = lane >> 4;

    int raw = blockIdx.x;
    int lg  = (raw & 7) * 64 + (raw >> 3);
    int cot = lg >> 7, pxt = lg & 127;
    int n = pxt >> 3, oh0 = (pxt & 7) * 4;

    f4 acc[4][4];
    #pragma unroll
    for (int m = 0; m < 4; ++m)
        #pragma unroll
        for (int nf = 0; nf < 4; ++nf)
            #pragma unroll
            for (int e = 0; e < 4; ++e) acc[m][nf][e] = 0.0f;

    #pragma unroll
    for (int k = 0; k < 8; ++k) {
        bf8v a_[4], b_[4];
        #pragma unroll
        for (int nf = 0; nf < 4; ++nf) {
            int oh = oh0 + wc * 2 + (nf >> 1);
            int ow = (nf & 1) * 16 + l15;
            b_[nf] = ld8(s2 + (((size_t)(n * 1024 + oh * 32 + ow)) << 8) + k * 32 + g * 8);
        }
        #pragma unroll
        for (int m = 0; m < 4; ++m) {
            int co = cot * 128 + wr * 64 + m * 16 + l15;
            a_[m] = ld8(wst + (size_t)co * 256 + k * 32 + g * 8);
        }
        #pragma unroll
        for (int m = 0; m < 4; ++m)
            #pragma unroll
            for (int nf = 0; nf < 4; ++nf)
                acc[m][nf] = __builtin_amdgcn_mfma_f32_16x16x32_bf16(
                    a_[m], b_[nf], acc[m][nf], 0, 0, 0);
    }
    #pragma unroll
    for (int m = 0; m < 4; ++m)
        #pragma unroll
        for (int nf = 0; nf < 4; ++nf) {
            f4 v = acc[m][nf];
            int oh = oh0 + wc * 2 + (nf >> 1);
            int ow = (nf & 1) * 16 + l15;
            int co = cot * 128 + wr * 64 + m * 16 + 4 * g;
            #pragma unroll
            for (int r = 0; r < 4; ++r)
                out[((size_t)(n * 512 + co + r)) * 1024 + oh * 32 + ow] = actf(v[r]);
        }
}

// ---------------------------------------------------------------------------
// conv1s: x1 = act(conv3x3(xb)) NHWC. Block 128co x 128px (2 rows x 64w),
// 4 waves (wave 64co x 64px), 4 ci-chunks of 64, LDS 33 KB -> 4 blocks/CU.
// Grid 1024 = 2 cot x 512 pxt, XCD-swizzled. Epilogue via swizzled LDS.
// ---------------------------------------------------------------------------
__global__ __launch_bounds__(256, 4) void k_conv1s(const __hip_bfloat16* __restrict__ xb,
                                                   const __hip_bfloat16* __restrict__ wA,
                                                   __hip_bfloat16* __restrict__ x1) {
    __shared__ uint4 smq[2112];                      // 33792 B
    char* smc = (char*)smq;
    const int tid  = threadIdx.x;
    const int lane = tid & 63;
    const int wid  = tid >> 6;
    const int wr = wid & 1, wc = wid >> 1;
    const int l15 = lane & 15, g = lane >> 4;

    int raw = blockIdx.x;
    int lg  = (raw & 7) * 128 + (raw >> 3);
    int cot = lg >> 9, pxt = lg & 511;
    int n = pxt >> 5, h0 = (pxt & 31) * 2;
    const size_t nb66 = (size_t)n * 64 * 66 * 256;
    const size_t nb   = (size_t)n * 4096 * 256;
    const char* wAc = (const char*)wA;

    f4 acc[4][4];
    #pragma unroll
    for (int m = 0; m < 4; ++m)
        #pragma unroll
        for (int nf = 0; nf < 4; ++nf)
            #pragma unroll
            for (int e = 0; e < 4; ++e) acc[m][nf][e] = 0.0f;

    #pragma unroll 1
    for (int ch = 0; ch < 4; ++ch) {
        if (ch) __syncthreads();
        // stage 4 rows x 66 wp x 64 ci = 33792 B (33 wave-loads, swizzled source)
        for (int li = wid; li < 33; li += 4) {
            int gi = li * 64 + lane;                 // 0..2111
            int row = (gi >= 1584) ? 3 : (gi >= 1056) ? 2 : (gi >= 528) ? 1 : 0;
            int rem = gi - row * 528;
            int wp = rem >> 3;
            int c8 = (rem & 7) ^ (wp & 7);
            int rc = h0 - 1 + row; rc = rc < 0 ? 0 : (rc > 63 ? 63 : rc);
            const __hip_bfloat16* src =
                xb + nb66 + (((size_t)(rc * 66 + wp)) << 8) + ch * 64 + c8 * 8;
            llds16(src, smc + li * 1024);
        }
        __syncthreads();

        #pragma unroll
        for (int kh = 0; kh < 3; ++kh) {
            int rrow = h0 + wc + kh - 1;
            bool rowok = (unsigned)rrow < 64u;       // wave-uniform
            #pragma unroll
            for (int kw = 0; kw < 3; ++kw) {
                #pragma unroll
                for (int qq = 0; qq < 2; ++qq) {
                    int c8r = qq * 4 + g;
                    bf8v b_[4];
                    #pragma unroll
                    for (int nf = 0; nf < 4; ++nf) {
                        int wp = nf * 16 + l15 + kw;           // 0..65, no clamp
                        int off = (wc + kh) * 8448 + (wp * 8 + (c8r ^ (wp & 7))) * 16;
                        bf8v v = *(const bf8v*)(smc + off);
                        bf8v z = {};
                        b_[nf] = rowok ? v : z;
                    }
                    int q = ch * 2 + qq;
                    #pragma unroll
                    for (int m = 0; m < 4; ++m) {
                        bf8v a = *(const bf8v*)(wAc +
                            ((size_t)(((kh * 3 + kw) * 8 + q) * 16 + cot * 8 + wr * 4 + m) << 10) +
                            (lane << 4));
                        #pragma unroll
                        for (int nf = 0; nf < 4; ++nf)
                            acc[m][nf] = __builtin_amdgcn_mfma_f32_16x16x32_bf16(
                                a, b_[nf], acc[m][nf], 0, 0, 0);
                    }
                }
            }
        }
    }

    // epilogue: act -> bf16, transpose via swizzled LDS, full-line stores
    __syncthreads();
    #pragma unroll
    for (int m = 0; m < 4; ++m)
        #pragma unroll
        for (int nf = 0; nf < 4; ++nf) {
            int p = wc * 64 + nf * 16 + l15;         // block-local px 0..127
            int co4 = wr * 16 + m * 4 + g;           // co granule 0..31
            int co4s = co4 ^ ((p & 15) << 1);
            union { unsigned long long u; unsigned short h4[4]; } pk;
            #pragma unroll
            for (int r = 0; r < 4; ++r) pk.h4[r] = f2bu(actf(acc[m][nf][r]));
            *reinterpret_cast<unsigned long long*>(smc + p * 256 + co4s * 8) = pk.u;
        }
    __syncthreads();
    {
        int p = tid >> 1, coh = tid & 1;
        int hh = h0 + (p >> 6), w = p & 63;
        __hip_bfloat16* dst = x1 + nb + (((size_t)(hh * 64 + w)) << 8) + cot * 128 + coh * 64;
        #pragma unroll
        for (int j = 0; j < 8; ++j) {
            int r2 = coh * 8 + j;                    // co octet 0..15
            int co4s = (2 * r2) ^ ((p & 15) << 1);
            uint4 v = *reinterpret_cast<const uint4*>(smc + p * 256 + co4s * 8);
            *reinterpret_cast<uint4*>(dst + j * 8) = v;
        }
    }
}

// ---------------------------------------------------------------------------
// fir1: xf = FIR4x4(x1, pad=2) NHWC bf16 [16][65][65][256]
// ---------------------------------------------------------------------------
__global__ __launch_bounds__(256) void k_fir1(const __hip_bfloat16* __restrict__ x1,
                                              __hip_bfloat16* __restrict__ xf) {
    int idx = blockIdx.x * 256 + threadIdx.x;  // 2,163,200
    int c8 = idx & 31; int rest = idx >> 5;
    int ow = rest % 65; rest /= 65;
    int oh = rest % 65; int n = rest / 65;
    int ci = c8 * 8;
    const float fk[4] = {0.125f, 0.375f, 0.375f, 0.125f};
    float a8[8];
    #pragma unroll
    for (int e = 0; e < 8; ++e) a8[e] = 0.0f;
    #pragma unroll
    for (int i = 0; i < 4; ++i) {
        int r = oh + i - 2;
        if (r < 0 || r >= 64) continue;
        #pragma unroll
        for (int j = 0; j < 4; ++j) {
            int c = ow + j - 2;
            if (c < 0 || c >= 64) continue;
            bf8v v = ld8(x1 + ((size_t)(n * 4096) + r * 64 + c) * 256 + ci);
            float fw = fk[i] * fk[j];
            #pragma unroll
            for (int e = 0; e < 8; ++e) a8[e] += fw * (float)v[e];
        }
    }
    union { uint4 q; unsigned short h8[8]; } pk;
    #pragma unroll
    for (int e = 0; e < 8; ++e) pk.h8[e] = f2bu(a8[e]);
    *reinterpret_cast<uint4*>(xf + ((size_t)n * 4225 + oh * 65 + ow) * 256 + ci) = pk.q;
}

// ---------------------------------------------------------------------------
// downs: out += act(conv3x3_s2(xf)). Block 128co x 64px (2 orows x 32),
// 4 waves (wave 32co x 64px), 8 ci-chunks of 32, LDS 21.5 KB -> 4 blocks/CU.
// Grid 1024 = 4 cot x 16 n x 16 oht, XCD-swizzled. No halo.
// ---------------------------------------------------------------------------
__global__ __launch_bounds__(256, 4) void k_downs(const __hip_bfloat16* __restrict__ xf,
                                                  const __hip_bfloat16* __restrict__ wD,
                                                  float* __restrict__ out) {
    __shared__ uint4 smq[1344];                      // 21504 B
    char* smc = (char*)smq;
    const int tid  = threadIdx.x;
    const int lane = tid & 63;
    const int wid  = tid >> 6;
    const int l15  = lane & 15, g = lane >> 4;

    int raw = blockIdx.x;
    int lg  = (raw & 7) * 128 + (raw >> 3);
    int cot = lg >> 8;                               // 0..3
    int rest = lg & 255;
    int n = rest >> 4, oht = rest & 15;
    int r0 = oht * 4;
    const size_t nxf = (size_t)n * 4225 * 256;
    const char* wDc = (const char*)wD;

    f4 acc[2][4];
    #pragma unroll
    for (int m = 0; m < 2; ++m)
        #pragma unroll
        for (int nf = 0; nf < 4; ++nf)
            #pragma unroll
            for (int e = 0; e < 4; ++e) acc[m][nf][e] = 0.0f;

    #pragma unroll 1
    for (int ch = 0; ch < 8; ++ch) {
        if (ch) __syncthreads();
        // stage 5 rows x 65 wp x 32 ci; granule = row*264 + wpair*8 + slot8
        for (int li = wid; li < 21; li += 4) {
            int gi = li * 64 + lane;
            if (gi > 1319) gi = 1319;
            int row = (gi >= 1056) ? 4 : (gi >= 792) ? 3 : (gi >= 528) ? 2 :
                      (gi >= 264) ? 1 : 0;
            int rem = gi - row * 264;
            int wpair = rem >> 3;
            int t4 = (rem & 7) ^ (wpair & 7);        // c8 + 4*odd
            int odd = t4 >> 2, c8 = t4 & 3;
            int wp = wpair * 2 + odd; if (wp > 64) wp = 64;
            const __hip_bfloat16* src = xf + nxf +
                (((size_t)((r0 + row) * 65 + wp)) << 8) + ch * 32 + c8 * 8;
            llds16(src, smc + li * 1024);
        }
        __syncthreads();

        #pragma unroll
        for (int kh = 0; kh < 3; ++kh) {
            #pragma unroll
            for (int kw = 0; kw < 3; ++kw) {
                bf8v b_[4];
                #pragma unroll
                for (int nf = 0; nf < 4; ++nf) {
                    int ow = (nf & 1) * 16 + l15;
                    int wp = 2 * ow + kw;
                    int wpair = wp >> 1, odd = wp & 1;
                    int s8 = (g + 4 * odd) ^ (wpair & 7);
                    int off = ((2 * (nf >> 1) + kh) * 264 + wpair * 8 + s8) * 16;
                    b_[nf] = *(const bf8v*)(smc + off);
                }
                #pragma unroll
                for (int m = 0; m < 2; ++m) {
                    bf8v a = *(const bf8v*)(wDc +
                        ((size_t)(((kh * 3 + kw) * 8 + ch) * 32 + cot * 8 + wid * 2 + m) << 10) +
                        (lane << 4));
                    #pragma unroll
                    for (int nf = 0; nf < 4; ++nf)
                        acc[m][nf] = __builtin_amdgcn_mfma_f32_16x16x32_bf16(
                            a, b_[nf], acc[m][nf], 0, 0, 0);
                }
            }
        }
    }

    #pragma unroll
    for (int m = 0; m < 2; ++m)
        #pragma unroll
        for (int nf = 0; nf < 4; ++nf) {
            f4 v = acc[m][nf];
            int oh = oht * 2 + (nf >> 1);
            int ow = (nf & 1) * 16 + l15;
            int co = cot * 128 + wid * 32 + m * 16 + 4 * g;
            #pragma unroll
            for (int r = 0; r < 4; ++r) {
                size_t oi = ((size_t)(n * 512 + co + r)) * 1024 + oh * 32 + ow;
                out[oi] += actf(v[r]);
            }
        }
}

// ---------------------------------------------------------------------------
extern "C" void kernel_launch(void* const* d_in, const int* in_sizes, int n_in,
                              void* d_out, int out_size, void* d_ws, size_t ws_size,
                              hipStream_t stream) {
    const float* lat   = (const float*)d_in[0];
    const float* wconv = (const float*)d_in[1];
    const float* wdown = (const float*)d_in[2];
    const float* wskip = (const float*)d_in[3];
    float* out = (float*)d_out;

    // ws layout (total 71,966,720 B, proven safe):
    //   region0 [0, 34,611,200): xb padded (34,603,008) then xf (34,611,200)
    //   x1 at 34,611,200 (33,554,432); s2 overlays x1 base (8,388,608 —
    //     dead before conv1s writes x1)
    //   wA 68,165,632 / wD 69,345,280 / wst 71,704,576
    char* base = (char*)d_ws;
    __hip_bfloat16* xb  = (__hip_bfloat16*)base;
    __hip_bfloat16* xf  = (__hip_bfloat16*)base;
    __hip_bfloat16* x1  = (__hip_bfloat16*)(base + 34611200);
    __hip_bfloat16* s2  = (__hip_bfloat16*)(base + 34611200);
    __hip_bfloat16* wA  = (__hip_bfloat16*)(base + 68165632);
    __hip_bfloat16* wD  = (__hip_bfloat16*)(base + 69345280);
    __hip_bfloat16* wst = (__hip_bfloat16*)(base + 71704576);

    hipLaunchKernelGGL(p_pad,   dim3(256),  dim3(256), 0, stream, xb);
    hipLaunchKernelGGL(p_xb,    dim3(8192), dim3(256), 0, stream, lat,   xb);
    hipLaunchKernelGGL(p_wA,    dim3(288),  dim3(256), 0, stream, wconv, wA);
    hipLaunchKernelGGL(p_wD,    dim3(576),  dim3(256), 0, stream, wdown, wD);
    hipLaunchKernelGGL(p_ws,    dim3(512),  dim3(256), 0, stream, wskip, wst);
    hipLaunchKernelGGL(k_fir2n, dim3(2048), dim3(256), 0, stream, xb, s2);
    hipLaunchKernelGGL(k_skipg, dim3(512),  dim3(256), 0, stream, s2, wst, out);
    hipLaunchKernelGGL(k_conv1s, dim3(1024), dim3(256), 0, stream, xb, wA, x1);
    hipLaunchKernelGGL(k_fir1,  dim3(8450), dim3(256), 0, stream, x1, xf);
    hipLaunchKernelGGL(k_downs, dim3(1024), dim3(256), 0, stream, xf, wD, out);
}